// Round 1
// baseline (12319.882 us; speedup 1.0000x reference)
//
#include <hip/hip_runtime.h>
#include <hip/hip_fp16.h>

#define NDIM   4096
#define LSTEPS 50
#define ANUM   4
#define NN     ((size_t)NDIM * (size_t)NDIM)
#define ROWQ   512            // uint4 per matrix row (4096 halves / 8)
#define RSTRIDE (5 * ROWQ)    // uint4 per row-group in interleaved [row][mat][col]

// persistent-kernel geometry: 1024 blocks x 256 thr = 4 blocks/CU on 256 CUs,
// launch_bounds(256,4) caps VGPR at 128 -> co-residency guaranteed.
#define NBLOCKS 1024
#define GRPS    16
#define BPG     (NBLOCKS / GRPS)   // 64 blocks per arrival group

typedef unsigned int nuint4 __attribute__((ext_vector_type(4)));

// workspace layout
#define MAT_BYTES ((size_t)(5 * NN * sizeof(__half)))                  // 160 MiB
#define X_BYTES   ((size_t)(LSTEPS + 1) * NDIM * sizeof(float))        // 51 state slots
#define BAR_LINES 33                                                   // root + 16 cnt + 16 gen
#define BAR_BYTES ((size_t)BAR_LINES * 128)

// ---------------------------------------------------------------------------
// Hierarchical device-scope grid barrier (all NBLOCKS co-resident).
// bar layout in 32-uint (128 B) lines: [0]=root, [1..16]=group counters,
// [17..32]=per-group generation lines (64 spinners per line, not 1024).
// Release: group leader -> root -> root-completer bumps all 16 gen lines.
// Failsafe: bounded spin (~65 ms) turns a residency bug into a wrong answer,
// never a hang.
// ---------------------------------------------------------------------------
__device__ __forceinline__ void grid_barrier(unsigned* __restrict__ bar, int bid) {
    __syncthreads();
    if (threadIdx.x == 0) {
        const int grp = bid & (GRPS - 1);
        unsigned* genp = bar + (size_t)(17 + grp) * 32;
        const unsigned g = __hip_atomic_load(genp, __ATOMIC_RELAXED,
                                             __HIP_MEMORY_SCOPE_AGENT);
        __threadfence();   // publish this block's x/mat writes device-wide
        const unsigned prev = __hip_atomic_fetch_add(bar + (size_t)(1 + grp) * 32, 1u,
                                   __ATOMIC_ACQ_REL, __HIP_MEMORY_SCOPE_AGENT);
        if ((prev & (BPG - 1)) == (unsigned)(BPG - 1)) {
            const unsigned rp = __hip_atomic_fetch_add(bar, 1u,
                                   __ATOMIC_ACQ_REL, __HIP_MEMORY_SCOPE_AGENT);
            if ((rp & (GRPS - 1)) == (unsigned)(GRPS - 1)) {
#pragma unroll
                for (int i = 0; i < GRPS; i++)
                    __hip_atomic_fetch_add(bar + (size_t)(17 + i) * 32, 1u,
                        __ATOMIC_RELEASE, __HIP_MEMORY_SCOPE_AGENT);
            }
        }
        int spins = 0;
        while (__hip_atomic_load(genp, __ATOMIC_ACQUIRE,
                                 __HIP_MEMORY_SCOPE_AGENT) == g) {
            __builtin_amdgcn_s_sleep(2);
            if (++spins > (1 << 20)) break;   // failsafe
        }
        __threadfence();   // acquire: invalidate stale L1/L2 before x reads
    }
    __syncthreads();
}

// zero the barrier state (must precede the persistent kernel; ws is re-poisoned)
__global__ void init_bar_kernel(unsigned* __restrict__ bar) {
    for (int i = threadIdx.x; i < BAR_LINES * 32; i += 256) bar[i] = 0u;
}

// ---------------------------------------------------------------------------
// ONE persistent kernel for the whole model:
//   phase A: fp32 [T_base|A_mats] -> fp16 interleaved (block converts its own
//            4 row-groups); phase B: x_1 = b
//   49 recurrence phases separated by grid barriers (identical inner math to
//   the verified step5_kernel: 5 fp32 accumulators, act-combine after K-loop)
//   tail: out[i] = r . x_{i+1} from the 51 retained state slots (atomic-free,
//         deterministic)
// ---------------------------------------------------------------------------
__global__ __launch_bounds__(256, 4) void fused_kernel(
        const float* __restrict__ Tb, const float* __restrict__ Am,
        const float* __restrict__ b,  const float* __restrict__ r,
        const float* __restrict__ traj,
        uint4* __restrict__ mats, float* __restrict__ xs,
        unsigned* __restrict__ bar, float* __restrict__ out) {
    const int tid = threadIdx.x;
    const int bid = blockIdx.x;
    __shared__ float parts[4];

    // ---- phase A: convert this block's 4 rows x 5 matrices (320 KB read) ----
    {
        const size_t dstBase = (size_t)bid * (4 * RSTRIDE);
#pragma unroll 4
        for (int k = 0; k < 40; k++) {
            const int off = tid + 256 * k;            // [0, 10240)
            const int rowLocal = off / RSTRIDE;
            const int rem = off - rowLocal * RSTRIDE;
            const int m = rem >> 9;
            const int c = rem & 511;
            const int row = bid * 4 + rowLocal;
            const float* src = (m == 0) ? Tb : (Am + (size_t)(m - 1) * NN);
            const float4* s4 = (const float4*)src;
            const size_t fi = (size_t)row * 1024 + 2 * (size_t)c;
            const float4 f0 = s4[fi];
            const float4 f1 = s4[fi + 1];
            union { uint4 v; __half h[8]; } pk;
            pk.h[0] = __float2half(f0.x); pk.h[1] = __float2half(f0.y);
            pk.h[2] = __float2half(f0.z); pk.h[3] = __float2half(f0.w);
            pk.h[4] = __float2half(f1.x); pk.h[5] = __float2half(f1.y);
            pk.h[6] = __float2half(f1.z); pk.h[7] = __float2half(f1.w);
            mats[dstBase + off] = pk.v;
        }
        // phase B: x_1 = b (slot 1), this block's 4 rows
        if (tid < 4) xs[NDIM + bid * 4 + tid] = b[bid * 4 + tid];
    }
    grid_barrier(bar, bid);

    // ---- recurrence: x_{t+1} = (T_base + sum_a act[a] A_a) x_t + b ----
    const int wave = tid >> 6, lane = tid & 63;
    const int row  = bid * 4 + wave;
    const size_t base = (size_t)row * RSTRIDE;
    const nuint4* M = (const nuint4*)mats;
    const float4* trajv = (const float4*)traj;

    for (int t = 1; t < LSTEPS; t++) {
        const float4* xv = (const float4*)(xs + (size_t)t * NDIM);
        const float4 av = trajv[t];
        float acc[5] = {0.f, 0.f, 0.f, 0.f, 0.f};
#pragma unroll
        for (int c = 0; c < 8; c++) {
            const int ci = c * 64 + lane;
            const float4 xa = xv[ci * 2];
            const float4 xb = xv[ci * 2 + 1];
#pragma unroll
            for (int m = 0; m < 5; m++) {
                union { nuint4 v; __half2 h2[4]; } u;
                u.v = M[base + (size_t)m * ROWQ + ci];
                const float2 p0 = __half22float2(u.h2[0]);
                const float2 p1 = __half22float2(u.h2[1]);
                const float2 p2 = __half22float2(u.h2[2]);
                const float2 p3 = __half22float2(u.h2[3]);
                float a = acc[m];
                a = fmaf(p0.x, xa.x, a); a = fmaf(p0.y, xa.y, a);
                a = fmaf(p1.x, xa.z, a); a = fmaf(p1.y, xa.w, a);
                a = fmaf(p2.x, xb.x, a); a = fmaf(p2.y, xb.y, a);
                a = fmaf(p3.x, xb.z, a); a = fmaf(p3.y, xb.w, a);
                acc[m] = a;
            }
        }
        float s = acc[0] + av.x * acc[1] + av.y * acc[2] + av.z * acc[3] + av.w * acc[4];
#pragma unroll
        for (int o = 32; o > 0; o >>= 1) s += __shfl_xor(s, o, 64);
        if (lane == 0) xs[(size_t)(t + 1) * NDIM + row] = s + b[row];
        grid_barrier(bar, bid);
    }

    // ---- tail: 50 reward dots, blocks 0..49, deterministic ----
    if (bid < LSTEPS) {
        const float* x = xs + (size_t)(bid + 1) * NDIM;
        float s = 0.f;
#pragma unroll
        for (int i = 0; i < 16; i++) {
            const int idx = tid + 256 * i;
            s = fmaf(r[idx], x[idx], s);
        }
#pragma unroll
        for (int o = 32; o > 0; o >>= 1) s += __shfl_xor(s, o, 64);
        if (lane == 0) parts[wave] = s;
        __syncthreads();
        if (tid == 0) out[bid] = parts[0] + parts[1] + parts[2] + parts[3];
    }
}

// ---------------------------------------------------------------------------
// Fallback path (ws too small for fp16 copy): unchanged fp32 multi-launch.
// ---------------------------------------------------------------------------
__global__ void init_kernel(const float* __restrict__ b, float* __restrict__ x1) {
    const int tid = threadIdx.x;
    const float4* bv = (const float4*)b;
    float4* xv = (float4*)x1;
#pragma unroll
    for (int i = 0; i < 4; i++) xv[tid + 256 * i] = bv[tid + 256 * i];
}

__global__ void dot_kernel(const float* __restrict__ x, const float* __restrict__ r,
                           float* __restrict__ out_elem) {
    const int tid = threadIdx.x;
    const int wave = tid >> 6, lane = tid & 63;
    __shared__ float parts[4];
    float s = 0.f;
#pragma unroll
    for (int i = 0; i < 16; i++) {
        const int idx = tid + 256 * i;
        s = fmaf(r[idx], x[idx], s);
    }
#pragma unroll
    for (int off = 32; off > 0; off >>= 1) s += __shfl_xor(s, off, 64);
    if (lane == 0) parts[wave] = s;
    __syncthreads();
    if (tid == 0) *out_elem = parts[0] + parts[1] + parts[2] + parts[3];
}

__global__ __launch_bounds__(256) void step_f32_kernel(
        const float* __restrict__ Tb, const float* __restrict__ Am,
        const float* __restrict__ x_in, float* __restrict__ x_out,
        const float* __restrict__ b, const float* __restrict__ r,
        const float* __restrict__ traj, float* __restrict__ out, int t) {
    const int tid  = threadIdx.x;
    const int wave = tid >> 6, lane = tid & 63;
    __shared__ float parts[4];

    if (blockIdx.x == gridDim.x - 1) {
        float s = 0.f;
#pragma unroll
        for (int i = 0; i < 16; i++) {
            const int idx = tid + 256 * i;
            s = fmaf(r[idx], x_in[idx], s);
        }
#pragma unroll
        for (int off = 32; off > 0; off >>= 1) s += __shfl_xor(s, off, 64);
        if (lane == 0) parts[wave] = s;
        __syncthreads();
        if (tid == 0) out[t - 1] = parts[0] + parts[1] + parts[2] + parts[3];
        return;
    }

    const float a0 = traj[t * ANUM + 0], a1 = traj[t * ANUM + 1],
                a2 = traj[t * ANUM + 2], a3 = traj[t * ANUM + 3];
    const int row = blockIdx.x * 4 + wave;
    const float4* mat[5] = {
        (const float4*)Tb, (const float4*)Am, (const float4*)(Am + NN),
        (const float4*)(Am + 2 * NN), (const float4*)(Am + 3 * NN)};
    const size_t rowq = (size_t)row * (NDIM / 4);
    const float4* xv = (const float4*)x_in;

    float acc[5] = {0.f, 0.f, 0.f, 0.f, 0.f};
#pragma unroll
    for (int c = 0; c < 16; c++) {
        const int ci = c * 64 + lane;
        const float4 xa = xv[ci];
        const size_t qi = rowq + ci;
#pragma unroll
        for (int m = 0; m < 5; m++) {
            const float4 v = mat[m][qi];
            float a = acc[m];
            a = fmaf(v.x, xa.x, a); a = fmaf(v.y, xa.y, a);
            a = fmaf(v.z, xa.z, a); a = fmaf(v.w, xa.w, a);
            acc[m] = a;
        }
    }
    float s = acc[0] + a0 * acc[1] + a1 * acc[2] + a2 * acc[3] + a3 * acc[4];
#pragma unroll
    for (int off = 32; off > 0; off >>= 1) s += __shfl_xor(s, off, 64);
    if (lane == 0) x_out[row] = s + b[row];
}

// ---------------------------------------------------------------------------
extern "C" void kernel_launch(void* const* d_in, const int* in_sizes, int n_in,
                              void* d_out, int out_size, void* d_ws, size_t ws_size,
                              hipStream_t stream) {
    // inputs: init_states(N) [unused], trajectories(L*ANUM), T_base(N*N),
    //         A_mats(ANUM*N*N), b(N), r(N)
    const float* traj = (const float*)d_in[1];
    const float* Tb   = (const float*)d_in[2];
    const float* Am   = (const float*)d_in[3];
    const float* b    = (const float*)d_in[4];
    const float* r    = (const float*)d_in[5];
    float* out = (float*)d_out;

    const size_t need = MAT_BYTES + X_BYTES + BAR_BYTES;   // ~161 MiB

    if (ws_size >= need) {
        uint4*    mats = (uint4*)d_ws;
        float*    xs   = (float*)((char*)d_ws + MAT_BYTES);
        unsigned* bar  = (unsigned*)((char*)d_ws + MAT_BYTES + X_BYTES);
        init_bar_kernel<<<1, 256, 0, stream>>>(bar);
        fused_kernel<<<NBLOCKS, 256, 0, stream>>>(Tb, Am, b, r, traj,
                                                  mats, xs, bar, out);
    } else {
        float* x0 = (float*)d_ws;
        float* x1 = x0 + NDIM;
        init_kernel<<<1, 256, 0, stream>>>(b, x0);
        for (int t = 1; t < LSTEPS; t++) {
            float* xi = (t & 1) ? x0 : x1;
            float* xo = (t & 1) ? x1 : x0;
            step_f32_kernel<<<NDIM / 4 + 1, 256, 0, stream>>>(Tb, Am, xi, xo, b, r,
                                                              traj, out, t);
        }
        dot_kernel<<<1, 256, 0, stream>>>(x1, r, out + (LSTEPS - 1));
    }
}

// Round 2
// 1610.964 us; speedup vs baseline: 7.6475x; 7.6475x over previous
//
#include <hip/hip_runtime.h>
#include <hip/hip_fp16.h>

#define NDIM   4096
#define LSTEPS 50
#define ANUM   4
#define NN     ((size_t)NDIM * (size_t)NDIM)
#define ROWQ   512            // uint4 per matrix row (4096 halves / 8)
#define RSTRIDE (5 * ROWQ)    // uint4 per row-group: [row][mat][col], 2560
#define LDSQ   128            // uint4-cols per (row,mat) cached in LDS (cols 0..1023)

// persistent geometry: 1024 blocks x 256 thr = 4 blocks/CU, LDS 40 KB/block
// (4 x 40 KB = full 160 KB/CU), launch_bounds(256,4) caps VGPR at 128.
#define NBLOCKS 1024
#define GRPS    16
#define BPG     (NBLOCKS / GRPS)

typedef unsigned int nuint4 __attribute__((ext_vector_type(4)));

#define MAT_BYTES ((size_t)(5 * NN * sizeof(__half)))                  // 160 MiB
#define X_BYTES   ((size_t)(LSTEPS + 1) * NDIM * sizeof(float))        // 51 slots
#define BAR_LINES 33
#define BAR_BYTES ((size_t)BAR_LINES * 128)

// ---------------------------------------------------------------------------
// Grid barrier, coherence-light version.
// ALL atomics RELAXED at AGENT scope: they execute at the coherence point
// (sc0 sc1) WITHOUT emitting buffer_inv/buffer_wbl2 — round 1's 8x regression
// was the ACQUIRE spin load invalidating the XCD's L1+L2 every poll.
// Ordering: __syncthreads() drains each wave's vmcnt before s_barrier, and all
// cross-block payload stores (x) are write-through AGENT atomics, so they are
// at the coherence point before the leader's arrival-add. No fences needed.
// Failsafe: bounded spin -> wrong answer, never a hang.
// ---------------------------------------------------------------------------
__device__ __forceinline__ void grid_barrier(unsigned* __restrict__ bar, int bid) {
    __syncthreads();
    if (threadIdx.x == 0) {
        const int grp = bid & (GRPS - 1);
        unsigned* genp = bar + (size_t)(17 + grp) * 32;
        const unsigned g = __hip_atomic_load(genp, __ATOMIC_RELAXED,
                                             __HIP_MEMORY_SCOPE_AGENT);
        const unsigned prev = __hip_atomic_fetch_add(bar + (size_t)(1 + grp) * 32, 1u,
                                   __ATOMIC_RELAXED, __HIP_MEMORY_SCOPE_AGENT);
        if ((prev & (BPG - 1)) == (unsigned)(BPG - 1)) {
            const unsigned rp = __hip_atomic_fetch_add(bar, 1u,
                                   __ATOMIC_RELAXED, __HIP_MEMORY_SCOPE_AGENT);
            if ((rp & (GRPS - 1)) == (unsigned)(GRPS - 1)) {
#pragma unroll
                for (int i = 0; i < GRPS; i++)
                    __hip_atomic_fetch_add(bar + (size_t)(17 + i) * 32, 1u,
                        __ATOMIC_RELAXED, __HIP_MEMORY_SCOPE_AGENT);
            }
        }
        int spins = 0;
        while (__hip_atomic_load(genp, __ATOMIC_RELAXED,
                                 __HIP_MEMORY_SCOPE_AGENT) == g) {
            __builtin_amdgcn_s_sleep(2);
            if (++spins > (1 << 20)) break;   // failsafe
        }
    }
    __syncthreads();
}

__global__ void init_bar_kernel(unsigned* __restrict__ bar) {
    for (int i = threadIdx.x; i < BAR_LINES * 32; i += 256) bar[i] = 0u;
}

// ---------------------------------------------------------------------------
// 5-matrix FMA body for one uint4 column index
// ---------------------------------------------------------------------------
__device__ __forceinline__ void fma5(const nuint4 v[5], const float4 xa,
                                     const float4 xb, float acc[5]) {
#pragma unroll
    for (int m = 0; m < 5; m++) {
        union { nuint4 v; __half2 h2[4]; } u;
        u.v = v[m];
        const float2 p0 = __half22float2(u.h2[0]);
        const float2 p1 = __half22float2(u.h2[1]);
        const float2 p2 = __half22float2(u.h2[2]);
        const float2 p3 = __half22float2(u.h2[3]);
        float a = acc[m];
        a = fmaf(p0.x, xa.x, a); a = fmaf(p0.y, xa.y, a);
        a = fmaf(p1.x, xa.z, a); a = fmaf(p1.y, xa.w, a);
        a = fmaf(p2.x, xb.x, a); a = fmaf(p2.y, xb.y, a);
        a = fmaf(p3.x, xb.z, a); a = fmaf(p3.y, xb.w, a);
        acc[m] = a;
    }
}

// ---------------------------------------------------------------------------
// Persistent fused kernel.
//  phase A : fp32 -> fp16 interleaved conv of this block's 4 rows (NT stores,
//            matrix data is block-local so needs NO cross-XCD coherence);
//            cols [0,1024) of all 5 mats additionally cached in LDS (40 KB);
//            x_1 = b written write-through.
//  steps   : 49 phases split LDS part (ci<128, free bandwidth) + streamed part
//            (ci 128..511). Streamed part alternates direction per step
//            (zigzag) so the XCD L2 retains the stream tail across steps.
//  tail    : 50 reward dots, deterministic, LDS reused for the 4-float scratch.
// ---------------------------------------------------------------------------
__global__ __launch_bounds__(256, 4) void fused_kernel(
        const float* __restrict__ Tb, const float* __restrict__ Am,
        const float* __restrict__ b,  const float* __restrict__ r,
        const float* __restrict__ traj,
        uint4* __restrict__ mats, float* __restrict__ xs,
        unsigned* __restrict__ bar, float* __restrict__ out) {
    const int tid = threadIdx.x;
    const int bid = blockIdx.x;

    __shared__ nuint4 cache[4][5][LDSQ];   // 40960 B: exactly 160 KB/CU at 4 blk/CU

    // ---- phase A ----
    {
        const size_t dstBase = (size_t)bid * (4 * RSTRIDE);
#pragma unroll 4
        for (int k = 0; k < 40; k++) {
            const int off = tid + 256 * k;            // [0, 10240)
            const int rowLocal = off / RSTRIDE;
            const int rem = off - rowLocal * RSTRIDE;
            const int m = rem >> 9;
            const int c = rem & 511;
            const int row = bid * 4 + rowLocal;
            const float* src = (m == 0) ? Tb : (Am + (size_t)(m - 1) * NN);
            const float4* s4 = (const float4*)src;
            const size_t fi = (size_t)row * 1024 + 2 * (size_t)c;
            const float4 f0 = s4[fi];
            const float4 f1 = s4[fi + 1];
            union { nuint4 v; __half h[8]; } pk;
            pk.h[0] = __float2half(f0.x); pk.h[1] = __float2half(f0.y);
            pk.h[2] = __float2half(f0.z); pk.h[3] = __float2half(f0.w);
            pk.h[4] = __float2half(f1.x); pk.h[5] = __float2half(f1.y);
            pk.h[6] = __float2half(f1.z); pk.h[7] = __float2half(f1.w);
            __builtin_nontemporal_store(pk.v, (nuint4*)&mats[dstBase + off]);
            if (c < LDSQ) cache[rowLocal][m][c] = pk.v;
        }
        // x_1 = b (slot 1), this block's 4 rows, write-through to coherence pt
        if (tid < 4)
            __hip_atomic_store(&xs[NDIM + bid * 4 + tid], b[bid * 4 + tid],
                               __ATOMIC_RELAXED, __HIP_MEMORY_SCOPE_AGENT);
    }
    grid_barrier(bar, bid);
    __threadfence();   // one-time insurance: drop any stale/poison lines

    // ---- recurrence ----
    const int wave = tid >> 6, lane = tid & 63;
    const int row  = bid * 4 + wave;
    const size_t base = (size_t)row * RSTRIDE;
    const nuint4* M = (const nuint4*)mats;
    const float4* trajv = (const float4*)traj;

    for (int t = 1; t < LSTEPS; t++) {
        const float4* xv = (const float4*)(xs + (size_t)t * NDIM);
        const float4 av = trajv[t];
        float acc[5] = {0.f, 0.f, 0.f, 0.f, 0.f};

        // LDS-resident columns [0,1024): ci in [0,128)
#pragma unroll
        for (int c = 0; c < 2; c++) {
            const int ci = c * 64 + lane;
            const float4 xa = xv[ci * 2];
            const float4 xb = xv[ci * 2 + 1];
            nuint4 v[5];
#pragma unroll
            for (int m = 0; m < 5; m++) v[m] = cache[wave][m][ci];
            fma5(v, xa, xb, acc);
        }
        // streamed columns [1024,4096): ci in [128,512), zigzag per step parity
        if (t & 1) {
#pragma unroll
            for (int cc = 0; cc < 6; cc++) {
                const int ci = (2 + cc) * 64 + lane;
                const float4 xa = xv[ci * 2];
                const float4 xb = xv[ci * 2 + 1];
                nuint4 v[5];
#pragma unroll
                for (int m = 0; m < 5; m++) v[m] = M[base + (size_t)m * ROWQ + ci];
                fma5(v, xa, xb, acc);
            }
        } else {
#pragma unroll
            for (int cc = 5; cc >= 0; cc--) {
                const int ci = (2 + cc) * 64 + lane;
                const float4 xa = xv[ci * 2];
                const float4 xb = xv[ci * 2 + 1];
                nuint4 v[5];
#pragma unroll
                for (int m = 0; m < 5; m++) v[m] = M[base + (size_t)m * ROWQ + ci];
                fma5(v, xa, xb, acc);
            }
        }

        float s = acc[0] + av.x * acc[1] + av.y * acc[2] + av.z * acc[3] + av.w * acc[4];
#pragma unroll
        for (int o = 32; o > 0; o >>= 1) s += __shfl_xor(s, o, 64);
        if (lane == 0)
            __hip_atomic_store(&xs[(size_t)(t + 1) * NDIM + row], s + b[row],
                               __ATOMIC_RELAXED, __HIP_MEMORY_SCOPE_AGENT);
        grid_barrier(bar, bid);
    }

    // ---- tail: 50 reward dots (LDS cache reused as scratch) ----
    if (bid < LSTEPS) {
        float* parts = (float*)cache;
        const float* x = xs + (size_t)(bid + 1) * NDIM;
        float s = 0.f;
#pragma unroll
        for (int i = 0; i < 16; i++) {
            const int idx = tid + 256 * i;
            s = fmaf(r[idx], x[idx], s);
        }
#pragma unroll
        for (int o = 32; o > 0; o >>= 1) s += __shfl_xor(s, o, 64);
        if (lane == 0) parts[wave] = s;
        __syncthreads();
        if (tid == 0) out[bid] = parts[0] + parts[1] + parts[2] + parts[3];
    }
}

// ---------------------------------------------------------------------------
// Fallback path (ws too small): unchanged fp32 multi-launch.
// ---------------------------------------------------------------------------
__global__ void init_kernel(const float* __restrict__ b, float* __restrict__ x1) {
    const int tid = threadIdx.x;
    const float4* bv = (const float4*)b;
    float4* xv = (float4*)x1;
#pragma unroll
    for (int i = 0; i < 4; i++) xv[tid + 256 * i] = bv[tid + 256 * i];
}

__global__ void dot_kernel(const float* __restrict__ x, const float* __restrict__ r,
                           float* __restrict__ out_elem) {
    const int tid = threadIdx.x;
    const int wave = tid >> 6, lane = tid & 63;
    __shared__ float parts[4];
    float s = 0.f;
#pragma unroll
    for (int i = 0; i < 16; i++) {
        const int idx = tid + 256 * i;
        s = fmaf(r[idx], x[idx], s);
    }
#pragma unroll
    for (int off = 32; off > 0; off >>= 1) s += __shfl_xor(s, off, 64);
    if (lane == 0) parts[wave] = s;
    __syncthreads();
    if (tid == 0) *out_elem = parts[0] + parts[1] + parts[2] + parts[3];
}

__global__ __launch_bounds__(256) void step_f32_kernel(
        const float* __restrict__ Tb, const float* __restrict__ Am,
        const float* __restrict__ x_in, float* __restrict__ x_out,
        const float* __restrict__ b, const float* __restrict__ r,
        const float* __restrict__ traj, float* __restrict__ out, int t) {
    const int tid  = threadIdx.x;
    const int wave = tid >> 6, lane = tid & 63;
    __shared__ float parts[4];

    if (blockIdx.x == gridDim.x - 1) {
        float s = 0.f;
#pragma unroll
        for (int i = 0; i < 16; i++) {
            const int idx = tid + 256 * i;
            s = fmaf(r[idx], x_in[idx], s);
        }
#pragma unroll
        for (int off = 32; off > 0; off >>= 1) s += __shfl_xor(s, off, 64);
        if (lane == 0) parts[wave] = s;
        __syncthreads();
        if (tid == 0) out[t - 1] = parts[0] + parts[1] + parts[2] + parts[3];
        return;
    }

    const float a0 = traj[t * ANUM + 0], a1 = traj[t * ANUM + 1],
                a2 = traj[t * ANUM + 2], a3 = traj[t * ANUM + 3];
    const int row = blockIdx.x * 4 + wave;
    const float4* mat[5] = {
        (const float4*)Tb, (const float4*)Am, (const float4*)(Am + NN),
        (const float4*)(Am + 2 * NN), (const float4*)(Am + 3 * NN)};
    const size_t rowq = (size_t)row * (NDIM / 4);
    const float4* xv = (const float4*)x_in;

    float acc[5] = {0.f, 0.f, 0.f, 0.f, 0.f};
#pragma unroll
    for (int c = 0; c < 16; c++) {
        const int ci = c * 64 + lane;
        const float4 xa = xv[ci];
        const size_t qi = rowq + ci;
#pragma unroll
        for (int m = 0; m < 5; m++) {
            const float4 v = mat[m][qi];
            float a = acc[m];
            a = fmaf(v.x, xa.x, a); a = fmaf(v.y, xa.y, a);
            a = fmaf(v.z, xa.z, a); a = fmaf(v.w, xa.w, a);
            acc[m] = a;
        }
    }
    float s = acc[0] + a0 * acc[1] + a1 * acc[2] + a2 * acc[3] + a3 * acc[4];
#pragma unroll
    for (int off = 32; off > 0; off >>= 1) s += __shfl_xor(s, off, 64);
    if (lane == 0) x_out[row] = s + b[row];
}

// ---------------------------------------------------------------------------
extern "C" void kernel_launch(void* const* d_in, const int* in_sizes, int n_in,
                              void* d_out, int out_size, void* d_ws, size_t ws_size,
                              hipStream_t stream) {
    const float* traj = (const float*)d_in[1];
    const float* Tb   = (const float*)d_in[2];
    const float* Am   = (const float*)d_in[3];
    const float* b    = (const float*)d_in[4];
    const float* r    = (const float*)d_in[5];
    float* out = (float*)d_out;

    const size_t need = MAT_BYTES + X_BYTES + BAR_BYTES;   // ~161 MiB

    if (ws_size >= need) {
        uint4*    mats = (uint4*)d_ws;
        float*    xs   = (float*)((char*)d_ws + MAT_BYTES);
        unsigned* bar  = (unsigned*)((char*)d_ws + MAT_BYTES + X_BYTES);
        init_bar_kernel<<<1, 256, 0, stream>>>(bar);
        fused_kernel<<<NBLOCKS, 256, 0, stream>>>(Tb, Am, b, r, traj,
                                                  mats, xs, bar, out);
    } else {
        float* x0 = (float*)d_ws;
        float* x1 = x0 + NDIM;
        init_kernel<<<1, 256, 0, stream>>>(b, x0);
        for (int t = 1; t < LSTEPS; t++) {
            float* xi = (t & 1) ? x0 : x1;
            float* xo = (t & 1) ? x1 : x0;
            step_f32_kernel<<<NDIM / 4 + 1, 256, 0, stream>>>(Tb, Am, xi, xo, b, r,
                                                              traj, out, t);
        }
        dot_kernel<<<1, 256, 0, stream>>>(x1, r, out + (LSTEPS - 1));
    }
}